// Round 11
// baseline (4899.252 us; speedup 1.0000x reference)
//
#include <hip/hip_runtime.h>
#include <math.h>

#define T_SEQ 1024
#define B_SZ  128
#define I_SZ  256
#define H_SZ  512
#define G_SZ  1536  // 3*H

#define NBS   8     // batch slices
#define NPC   4     // pair clusters (2 slices per block)
#define MB    16    // batch per slice
#define NHS   8     // h slices = blocks per cluster
#define HB    64    // h cols per block
#define GB    192   // gate cols per block (3*HB)
#define NTHR  384   // 6 waves
#define PGB   384   // proj: gate cols per block
#define PH    (MB * H_SZ)      // one phase region: 8192 f16 (16 KB)
#define SLC   (3 * PH)         // per batch-slice hbuf: 3 phases

#define SENT32 0x7FFF7FFFu  // two f16 NaNs; h clipped to +-5 so never legit

typedef _Float16 f16;
typedef _Float16 half8 __attribute__((ext_vector_type(8)));
typedef _Float16 f16x4 __attribute__((ext_vector_type(4)));
typedef float f32x4 __attribute__((ext_vector_type(4)));
typedef unsigned uint32x2 __attribute__((ext_vector_type(2)));
typedef unsigned uint32x4 __attribute__((ext_vector_type(4)));

// ---- MALL-coherent (sc0 sc1) ops: bypass L1/L2; device-wide coherent ----
__device__ __forceinline__ f32x4 cload_f4(const void* p) {
    f32x4 v;
    asm volatile("global_load_dwordx4 %0, %1, off sc0 sc1" : "=v"(v) : "v"(p));
    return v;
}
__device__ __forceinline__ void cstore_f4(void* p, f32x4 v) {
    asm volatile("global_store_dwordx4 %0, %1, off sc0 sc1" :: "v"(p), "v"(v) : "memory");
}
__device__ __forceinline__ void cstore_u2(void* p, uint32x2 v) {
    asm volatile("global_store_dwordx2 %0, %1, off sc0 sc1" :: "v"(p), "v"(v) : "memory");
}
__device__ __forceinline__ f16x4 load_f16x4_nw(const void* p) {
    f16x4 v;
    asm volatile("global_load_dwordx2 %0, %1, off" : "=v"(v) : "v"(p));
    return v;
}
__device__ __forceinline__ void wait_vm0() {
    asm volatile("s_waitcnt vmcnt(0)" ::: "memory");
    __builtin_amdgcn_sched_barrier(0);
}
__device__ __forceinline__ bool stale4(f32x4 v) {
    uint32x4 u = __builtin_bit_cast(uint32x4, v);
    return (u[0] == SENT32) | (u[1] == SENT32) | (u[2] == SENT32) | (u[3] == SENT32);
}

// ---------------------------------------------------------------------------
// Setup: w_ih -> f16 [g][i]; w_hh -> f16 slices [hs=8][GB=192][512]
// (gl<96 = register tiles, gl>=96 = LDS tiles); hbuf[slice][3][16][512]:
// phase0 <- h0 broadcast, phases 1,2 <- sentinel.
// ---------------------------------------------------------------------------
__global__ void setup_kernel(const float* __restrict__ w_ih,
                             const float* __restrict__ w_hh,
                             const float* __restrict__ h0,
                             f16* __restrict__ wp16,
                             f16* __restrict__ wf16,
                             f16* __restrict__ hbuf) {
    const int i0 = blockIdx.x * blockDim.x + threadIdx.x;
    const int stride = gridDim.x * blockDim.x;
    for (int i = i0; i < I_SZ * G_SZ; i += stride)
        wp16[i] = (f16)w_ih[i];
    for (int i = i0; i < NHS * GB * H_SZ; i += stride) {
        int hs  = i / (GB * H_SZ);
        int rem = i % (GB * H_SZ);
        int gl = rem / H_SZ, k = rem % H_SZ;
        int gate = gl >> 6, c = gl & 63;
        int gg = gate * H_SZ + hs * HB + c;
        wf16[i] = (f16)w_hh[(size_t)gg * H_SZ + k];
    }
    const int htot = NBS * SLC;   // 196608
    const f16 sent = __builtin_bit_cast(f16, (unsigned short)0x7FFF);
    for (int i = i0; i < htot; i += stride) {
        int j = i % SLC;
        int phase = j / PH;
        hbuf[i] = (phase == 0) ? (f16)h0[j & (H_SZ - 1)] : sent;
    }
}

// ---------------------------------------------------------------------------
// Input projection, f16 MFMA (passed R7/R9/R10, unchanged). Dense gi layout:
// gi16[((t*NBS + bs)*G + g)*MB + m],  bs = b>>4, m = b&15.
// ---------------------------------------------------------------------------
__global__ __launch_bounds__(512, 1)
void proj_kernel(const float* __restrict__ x,
                 const f16* __restrict__ wp16,
                 const float* __restrict__ b_ih,
                 f16* __restrict__ gi16) {
    const int t  = blockIdx.x >> 2;
    const int g0 = (blockIdx.x & 3) * PGB;
    const int tid  = threadIdx.x;
    const int wid  = tid >> 6;
    const int lane = tid & 63;
    const int col  = lane & 15;
    const int krow = lane >> 4;

    __shared__ __align__(16) unsigned char x_lds[128 * 512];  // [b][k] f16, 64 KB

    #pragma unroll
    for (int j = 0; j < 8; ++j) {
        int idx = tid + j * 512;
        int b = idx >> 5, k16 = idx & 31;
        const float* xp = x + ((size_t)b * T_SEQ + t) * I_SZ + k16 * 8;
        float4 v0 = *reinterpret_cast<const float4*>(xp);
        float4 v1 = *reinterpret_cast<const float4*>(xp + 4);
        half8 hv;
        hv[0] = (f16)v0.x; hv[1] = (f16)v0.y; hv[2] = (f16)v0.z; hv[3] = (f16)v0.w;
        hv[4] = (f16)v1.x; hv[5] = (f16)v1.y; hv[6] = (f16)v1.z; hv[7] = (f16)v1.w;
        unsigned addr = ((unsigned)(b * 512 + k16 * 16)) ^ (((unsigned)(b & 7)) << 4);
        *reinterpret_cast<half8*>(x_lds + addr) = hv;
    }

    const int gw0 = g0 + wid * 48;
    half8 af[3][8];
    #pragma unroll
    for (int m = 0; m < 3; ++m)
        #pragma unroll
        for (int k = 0; k < 8; ++k)
            af[m][k] = *reinterpret_cast<const half8*>(
                wp16 + (size_t)(gw0 + m * 16 + col) * I_SZ + k * 32 + krow * 8);

    float bias[3][4];
    #pragma unroll
    for (int m = 0; m < 3; ++m)
        #pragma unroll
        for (int r = 0; r < 4; ++r)
            bias[m][r] = b_ih[gw0 + m * 16 + krow * 4 + r];

    __syncthreads();

    #pragma unroll
    for (int nt = 0; nt < 8; ++nt) {
        const int b0 = nt * 16;
        f32x4 acc0 = {0.f,0.f,0.f,0.f}, acc1 = {0.f,0.f,0.f,0.f}, acc2 = {0.f,0.f,0.f,0.f};
        const int brow = b0 + col;
        const unsigned bswz = ((unsigned)(brow & 7)) << 4;
        #pragma unroll
        for (int k = 0; k < 8; ++k) {
            half8 bf = *reinterpret_cast<const half8*>(
                x_lds + (((unsigned)(brow * 512 + k * 64 + krow * 16)) ^ bswz));
            acc0 = __builtin_amdgcn_mfma_f32_16x16x32_f16(af[0][k], bf, acc0, 0, 0, 0);
            acc1 = __builtin_amdgcn_mfma_f32_16x16x32_f16(af[1][k], bf, acc1, 0, 0, 0);
            acc2 = __builtin_amdgcn_mfma_f32_16x16x32_f16(af[2][k], bf, acc2, 0, 0, 0);
        }
        const int pbs = brow >> 4;
        const int pm  = brow & 15;
        #pragma unroll
        for (int r = 0; r < 4; ++r) {
            int gr = gw0 + krow * 4 + r;
            gi16[((size_t)(t * NBS + pbs) * G_SZ + gr)      * MB + pm] = (f16)(acc0[r] + bias[0][r]);
            gi16[((size_t)(t * NBS + pbs) * G_SZ + gr + 16) * MB + pm] = (f16)(acc1[r] + bias[1][r]);
            gi16[((size_t)(t * NBS + pbs) * G_SZ + gr + 32) * MB + pm] = (f16)(acc2[r] + bias[2][r]);
        }
    }
}

// ---------------------------------------------------------------------------
// Persistent GRU: 32 blocks = 4 pair-clusters x 8 h-slices. Two independent
// batch-slice chains (A,B) per block share one weight set: 1 reg tile/wave
// (16 x half8 = 64 VGPR, proven resident) + 6 tiles in LDS (96 KB, swizzled).
// R10's 3-phase sentinel-pull per chain; A/B interleave hides publish->
// visible latency; NHS=8 halves coherent read traffic.
// ---------------------------------------------------------------------------
__global__ __launch_bounds__(NTHR, 1)
void gru_persist(const f16* __restrict__ gi,      // [T][NBS][G][MB] f16
                 const f16* __restrict__ wf16,    // [NHS][GB][512]
                 const float* __restrict__ h0,
                 const float* __restrict__ b_hh,
                 f16* __restrict__ hbuf,          // [NBS][3][16][512] f16
                 float* __restrict__ out) {
    const int pcid = blockIdx.x & (NPC - 1);
    const int hs   = blockIdx.x >> 2;      // 0..7
    const int bsA  = pcid * 2;
    const int bsB  = pcid * 2 + 1;
    const int tid  = threadIdx.x;

    __shared__ __align__(16) unsigned char w_lds[96 * 1024];      // 96 KB
    __shared__ __align__(16) unsigned char h_lds[MB * H_SZ * 2];  // 16 KB
    __shared__ float act_r[MB][HB + 1];
    __shared__ float act_z[MB][HB + 1];
    __shared__ float act_n[MB][HB + 1];
    __shared__ float act_i[MB][HB + 1];

    const int wid  = tid >> 6;
    const int lane = tid & 63;
    const int col  = lane & 15;
    const int krow = lane >> 4;

    const int ttR = wid, ttL = wid + 6;
    const int gateR = ttR >> 2, gateL = ttL >> 2;   // R: 0,0,0,0,1,1  L: 1,1,2,2,2,2
    const int gcR = (ttR & 3) * 16 + col;
    const int gcL = (ttL & 3) * 16 + col;
    const int ggR = gateR * H_SZ + hs * HB + gcR;
    const int ggL = gateL * H_SZ + hs * HB + gcL;
    const float biasR = b_hh[ggR];
    const float biasL = b_hh[ggL];

    const f16* wbase = wf16 + (size_t)hs * GB * H_SZ;

    for (int i = tid; i < 96 * 64; i += NTHR) {     // LDS tiles: 6144 x 16B
        int r = i >> 6, k8 = i & 63;
        f32x4 v = *reinterpret_cast<const f32x4*>(
            wbase + (size_t)(96 + r) * H_SZ + k8 * 8);
        unsigned addr = ((unsigned)(r * 1024 + k8 * 16)) ^ (((unsigned)(r & 7)) << 4);
        *reinterpret_cast<f32x4*>(w_lds + addr) = v;
    }
    half8 bfrag[16];   // reg tile: the proven-resident shape
    {
        const f16* wp = wbase + (size_t)(ttR * 16 + col) * H_SZ + krow * 8;
        #pragma unroll
        for (int kk = 0; kk < 16; ++kk)
            bfrag[kk] = *reinterpret_cast<const half8*>(wp + kk * 32);
    }

    const int cb  = tid >> 4;
    const int cc4 = (tid & 15) * 4;
    f32x4 hmA = {0.f,0.f,0.f,0.f}, hmB = {0.f,0.f,0.f,0.f};
    if (tid < 256) {
        #pragma unroll
        for (int u = 0; u < 4; ++u) { hmA[u] = h0[hs * HB + cc4 + u]; hmB[u] = hmA[u]; }
    }

    const unsigned a_base = (unsigned)(col * 1024 + krow * 16);
    const unsigned a_swz  = ((unsigned)(col & 7)) << 4;
    const unsigned b_base = (unsigned)((wid * 16 + col) * 1024 + krow * 16);

    const int i0 = tid, i1 = tid + NTHR, i2 = tid + 2 * NTHR;
    const bool has2 = (tid < 256);
    const f32x4 sentv = __builtin_bit_cast(f32x4,
        (uint32x4){SENT32, SENT32, SENT32, SENT32});

    f16* hbA = hbuf + (size_t)bsA * SLC;
    f16* hbB = hbuf + (size_t)bsB * SLC;

    __syncthreads();

    for (int t = 0; t < T_SEQ; ++t) {
        const size_t pcO = (size_t)(t % 3) * PH;
        const size_t pnO = (size_t)((t + 1) % 3) * PH;
        const size_t paO = (size_t)((t + 2) % 3) * PH;

        auto chain = [&](f16* hb, int bs, f32x4& hm) {
            f16x4 gvR = load_f16x4_nw(
                gi + ((size_t)(t * NBS + bs) * G_SZ + ggR) * MB + krow * 4);
            f16x4 gvL = load_f16x4_nw(
                gi + ((size_t)(t * NBS + bs) * G_SZ + ggL) * MB + krow * 4);

            const f16* hin = hb + pcO;
            const f16* a0p = hin + (i0 >> 6) * H_SZ + (i0 & 63) * 8;
            const f16* a1p = hin + (i1 >> 6) * H_SZ + (i1 & 63) * 8;
            const f16* a2p = hin + (i2 >> 6) * H_SZ + (i2 & 63) * 8;
            f32x4 v0 = cload_f4(a0p);
            f32x4 v1 = cload_f4(a1p);
            f32x4 v2;
            if (has2) v2 = cload_f4(a2p);
            wait_vm0();
            {
                int guard = 0;
                bool s0 = stale4(v0), s1 = stale4(v1), s2 = has2 && stale4(v2);
                while (__any(s0 | s1 | s2)) {
                    if (s0) v0 = cload_f4((const void*)a0p);
                    if (s1) v1 = cload_f4((const void*)a1p);
                    if (s2) v2 = cload_f4((const void*)a2p);
                    wait_vm0();
                    s0 = stale4(v0); s1 = stale4(v1); s2 = has2 && stale4(v2);
                    if (++guard > (1 << 20)) break;   // safety valve
                }
            }

            {
                unsigned l0 = ((unsigned)((i0 >> 6) * 1024 + (i0 & 63) * 16))
                              ^ (((unsigned)((i0 >> 6) & 7)) << 4);
                *reinterpret_cast<f32x4*>(h_lds + l0) = v0;
                unsigned l1 = ((unsigned)((i1 >> 6) * 1024 + (i1 & 63) * 16))
                              ^ (((unsigned)((i1 >> 6) & 7)) << 4);
                *reinterpret_cast<f32x4*>(h_lds + l1) = v1;
                if (has2) {
                    unsigned l2 = ((unsigned)((i2 >> 6) * 1024 + (i2 & 63) * 16))
                                  ^ (((unsigned)((i2 >> 6) & 7)) << 4);
                    *reinterpret_cast<f32x4*>(h_lds + l2) = v2;
                }
                if (tid < 128) {
                    int row = tid >> 3, g = tid & 7;
                    cstore_f4(hb + paO + (size_t)row * H_SZ + hs * HB + g * 8,
                              sentv);
                }
            }
            __syncthreads();

            f32x4 accR = {0.f,0.f,0.f,0.f}, accL = {0.f,0.f,0.f,0.f};
            #pragma unroll
            for (int kk = 0; kk < 16; ++kk) {
                half8 av = *reinterpret_cast<const half8*>(
                    h_lds + ((a_base + kk * 64) ^ a_swz));
                half8 bv = *reinterpret_cast<const half8*>(
                    w_lds + ((b_base + kk * 64) ^ a_swz));
                accR = __builtin_amdgcn_mfma_f32_16x16x32_f16(av, bfrag[kk], accR, 0, 0, 0);
                accL = __builtin_amdgcn_mfma_f32_16x16x32_f16(av, bv,        accL, 0, 0, 0);
            }
            wait_vm0();   // arm stores + gi retired (hidden under MFMA) [protocol-critical]

            // raw pre-activations to LDS; combine applies the nonlinearity
            if (gateR == 0) {
                #pragma unroll
                for (int r = 0; r < 4; ++r)
                    act_r[krow * 4 + r][gcR] = accR[r] + biasR + (float)gvR[r];
            } else {
                #pragma unroll
                for (int r = 0; r < 4; ++r)
                    act_z[krow * 4 + r][gcR] = accR[r] + biasR + (float)gvR[r];
            }
            if (gateL == 1) {
                #pragma unroll
                for (int r = 0; r < 4; ++r)
                    act_z[krow * 4 + r][gcL] = accL[r] + biasL + (float)gvL[r];
            } else {
                #pragma unroll
                for (int r = 0; r < 4; ++r) {
                    act_n[krow * 4 + r][gcL] = accL[r] + biasL;
                    act_i[krow * 4 + r][gcL] = (float)gvL[r];
                }
            }
            __syncthreads();

            if (tid < 256) {
                float h4[4];
                unsigned short us[4];
                #pragma unroll
                for (int u = 0; u < 4; ++u) {
                    int c = cc4 + u;
                    float r = 1.f / (1.f + __expf(-act_r[cb][c]));
                    float z = 1.f / (1.f + __expf(-act_z[cb][c]));
                    float a = act_i[cb][c] + r * act_n[cb][c];
                    float n = 1.f - 2.f / (__expf(2.f * a) + 1.f);
                    float hn = (1.f - z) * n + z * hm[u];
                    hn = fminf(fmaxf(hn, -5.f), 5.f);
                    hm[u] = hn;
                    h4[u] = hn;
                    us[u] = __builtin_bit_cast(unsigned short, (f16)hn);
                }
                uint32x2 pk;
                pk[0] = (unsigned)us[0] | ((unsigned)us[1] << 16);
                pk[1] = (unsigned)us[2] | ((unsigned)us[3] << 16);
                const int hg = hs * HB + cc4;
                cstore_u2(hb + pnO + (size_t)cb * H_SZ + hg, pk);   // publish

                const int bg = bs * MB + cb;
                *reinterpret_cast<float4*>(
                    out + ((size_t)bg * T_SEQ + t) * H_SZ + hg) =
                    make_float4(h4[0], h4[1], h4[2], h4[3]);
                if (t == T_SEQ - 1)
                    *reinterpret_cast<float4*>(
                        out + (size_t)B_SZ * T_SEQ * H_SZ + (size_t)bg * H_SZ + hg) =
                        make_float4(h4[0], h4[1], h4[2], h4[3]);
            }
        };

        chain(hbA, bsA, hmA);
        chain(hbB, bsB, hmB);
    }
}

// ---------------------------------------------------------------------------
extern "C" void kernel_launch(void* const* d_in, const int* in_sizes, int n_in,
                              void* d_out, int out_size, void* d_ws, size_t ws_size,
                              hipStream_t stream) {
    const float* x    = (const float*)d_in[0];
    const float* h0   = (const float*)d_in[1];
    const float* w_ih = (const float*)d_in[2];
    const float* w_hh = (const float*)d_in[3];
    const float* b_ih = (const float*)d_in[4];
    const float* b_hh = (const float*)d_in[5];
    float* out = (float*)d_out;

    char* p = (char*)d_ws;
    f16* wp16 = (f16*)p;   p += (size_t)I_SZ * G_SZ * 2;            // 768 KB
    f16* wf16 = (f16*)p;   p += (size_t)NHS * GB * H_SZ * 2;        // 1.5 MB
    f16* hbuf = (f16*)p;   p += (size_t)NBS * SLC * 2;              // 384 KB
    f16* gi   = (f16*)p;   // [T][NBS][G][MB] f16 = 402 MB (ws >= 810 MB proven)

    setup_kernel<<<512, 256, 0, stream>>>(w_ih, w_hh, h0, wp16, wf16, hbuf);

    proj_kernel<<<T_SEQ * 4, 512, 0, stream>>>(x, wp16, b_ih, gi);

    gru_persist<<<NPC * NHS, NTHR, 0, stream>>>(gi, wf16, h0, b_hh, hbuf, out);
}

// Round 12
// 3185.526 us; speedup vs baseline: 1.5380x; 1.5380x over previous
//
#include <hip/hip_runtime.h>
#include <math.h>

#define T_SEQ 1024
#define B_SZ  128
#define I_SZ  256
#define H_SZ  512
#define G_SZ  1536  // 3*H

#define NBS   8     // batch slices (clusters)
#define MB    16    // batch per slice
#define NHS   8     // h slices = blocks per cluster
#define HB    64    // h cols per block
#define GB    192   // gate cols per block (3*HB)
#define NTHR  384   // 6 waves
#define PGB   384   // proj: gate cols per block
#define PH    (MB * H_SZ)      // one phase region: 8192 f16 (16 KB)
#define SLC   (3 * PH)         // per batch-slice hbuf: 3 phases

#define SENT32 0x7FFF7FFFu  // two f16 NaNs; h clipped to +-5 so never legit

typedef _Float16 f16;
typedef _Float16 half8 __attribute__((ext_vector_type(8)));
typedef _Float16 f16x4 __attribute__((ext_vector_type(4)));
typedef float f32x4 __attribute__((ext_vector_type(4)));
typedef unsigned uint32x2 __attribute__((ext_vector_type(2)));
typedef unsigned uint32x4 __attribute__((ext_vector_type(4)));

// ---- MALL-coherent (sc0 sc1) ops: bypass L1/L2; device-wide coherent ----
__device__ __forceinline__ f32x4 cload_f4(const void* p) {
    f32x4 v;
    asm volatile("global_load_dwordx4 %0, %1, off sc0 sc1" : "=v"(v) : "v"(p));
    return v;
}
__device__ __forceinline__ void cstore_f4(void* p, f32x4 v) {
    asm volatile("global_store_dwordx4 %0, %1, off sc0 sc1" :: "v"(p), "v"(v) : "memory");
}
__device__ __forceinline__ void cstore_u2(void* p, uint32x2 v) {
    asm volatile("global_store_dwordx2 %0, %1, off sc0 sc1" :: "v"(p), "v"(v) : "memory");
}
__device__ __forceinline__ f16x4 load_f16x4_nw(const void* p) {
    f16x4 v;
    asm volatile("global_load_dwordx2 %0, %1, off" : "=v"(v) : "v"(p));
    return v;
}
__device__ __forceinline__ void wait_vm0() {
    asm volatile("s_waitcnt vmcnt(0)" ::: "memory");
    __builtin_amdgcn_sched_barrier(0);
}
__device__ __forceinline__ bool stale4(f32x4 v) {
    uint32x4 u = __builtin_bit_cast(uint32x4, v);
    return (u[0] == SENT32) | (u[1] == SENT32) | (u[2] == SENT32) | (u[3] == SENT32);
}

// ---------------------------------------------------------------------------
// Setup: w_ih -> f16 [g][i]; w_hh -> f16 slices [hs=8][GB=192][512]
// (gl<96 = register tiles, gl>=96 = LDS tiles); hbuf[slice][3][16][512]:
// phase0 <- h0 broadcast, phases 1,2 <- sentinel.
// ---------------------------------------------------------------------------
__global__ void setup_kernel(const float* __restrict__ w_ih,
                             const float* __restrict__ w_hh,
                             const float* __restrict__ h0,
                             f16* __restrict__ wp16,
                             f16* __restrict__ wf16,
                             f16* __restrict__ hbuf) {
    const int i0 = blockIdx.x * blockDim.x + threadIdx.x;
    const int stride = gridDim.x * blockDim.x;
    for (int i = i0; i < I_SZ * G_SZ; i += stride)
        wp16[i] = (f16)w_ih[i];
    for (int i = i0; i < NHS * GB * H_SZ; i += stride) {
        int hs  = i / (GB * H_SZ);
        int rem = i % (GB * H_SZ);
        int gl = rem / H_SZ, k = rem % H_SZ;
        int gate = gl >> 6, c = gl & 63;
        int gg = gate * H_SZ + hs * HB + c;
        wf16[i] = (f16)w_hh[(size_t)gg * H_SZ + k];
    }
    const int htot = NBS * SLC;   // 196608
    const f16 sent = __builtin_bit_cast(f16, (unsigned short)0x7FFF);
    for (int i = i0; i < htot; i += stride) {
        int j = i % SLC;
        int phase = j / PH;
        hbuf[i] = (phase == 0) ? (f16)h0[j & (H_SZ - 1)] : sent;
    }
}

// ---------------------------------------------------------------------------
// Input projection, f16 MFMA (passed R7/R9/R10/R11, unchanged). Dense gi:
// gi16[((t*NBS + bs)*G + g)*MB + m],  bs = b>>4, m = b&15.
// ---------------------------------------------------------------------------
__global__ __launch_bounds__(512, 1)
void proj_kernel(const float* __restrict__ x,
                 const f16* __restrict__ wp16,
                 const float* __restrict__ b_ih,
                 f16* __restrict__ gi16) {
    const int t  = blockIdx.x >> 2;
    const int g0 = (blockIdx.x & 3) * PGB;
    const int tid  = threadIdx.x;
    const int wid  = tid >> 6;
    const int lane = tid & 63;
    const int col  = lane & 15;
    const int krow = lane >> 4;

    __shared__ __align__(16) unsigned char x_lds[128 * 512];  // [b][k] f16, 64 KB

    #pragma unroll
    for (int j = 0; j < 8; ++j) {
        int idx = tid + j * 512;
        int b = idx >> 5, k16 = idx & 31;
        const float* xp = x + ((size_t)b * T_SEQ + t) * I_SZ + k16 * 8;
        float4 v0 = *reinterpret_cast<const float4*>(xp);
        float4 v1 = *reinterpret_cast<const float4*>(xp + 4);
        half8 hv;
        hv[0] = (f16)v0.x; hv[1] = (f16)v0.y; hv[2] = (f16)v0.z; hv[3] = (f16)v0.w;
        hv[4] = (f16)v1.x; hv[5] = (f16)v1.y; hv[6] = (f16)v1.z; hv[7] = (f16)v1.w;
        unsigned addr = ((unsigned)(b * 512 + k16 * 16)) ^ (((unsigned)(b & 7)) << 4);
        *reinterpret_cast<half8*>(x_lds + addr) = hv;
    }

    const int gw0 = g0 + wid * 48;
    half8 af[3][8];
    #pragma unroll
    for (int m = 0; m < 3; ++m)
        #pragma unroll
        for (int k = 0; k < 8; ++k)
            af[m][k] = *reinterpret_cast<const half8*>(
                wp16 + (size_t)(gw0 + m * 16 + col) * I_SZ + k * 32 + krow * 8);

    float bias[3][4];
    #pragma unroll
    for (int m = 0; m < 3; ++m)
        #pragma unroll
        for (int r = 0; r < 4; ++r)
            bias[m][r] = b_ih[gw0 + m * 16 + krow * 4 + r];

    __syncthreads();

    #pragma unroll
    for (int nt = 0; nt < 8; ++nt) {
        const int b0 = nt * 16;
        f32x4 acc0 = {0.f,0.f,0.f,0.f}, acc1 = {0.f,0.f,0.f,0.f}, acc2 = {0.f,0.f,0.f,0.f};
        const int brow = b0 + col;
        const unsigned bswz = ((unsigned)(brow & 7)) << 4;
        #pragma unroll
        for (int k = 0; k < 8; ++k) {
            half8 bf = *reinterpret_cast<const half8*>(
                x_lds + (((unsigned)(brow * 512 + k * 64 + krow * 16)) ^ bswz));
            acc0 = __builtin_amdgcn_mfma_f32_16x16x32_f16(af[0][k], bf, acc0, 0, 0, 0);
            acc1 = __builtin_amdgcn_mfma_f32_16x16x32_f16(af[1][k], bf, acc1, 0, 0, 0);
            acc2 = __builtin_amdgcn_mfma_f32_16x16x32_f16(af[2][k], bf, acc2, 0, 0, 0);
        }
        const int pbs = brow >> 4;
        const int pm  = brow & 15;
        #pragma unroll
        for (int r = 0; r < 4; ++r) {
            int gr = gw0 + krow * 4 + r;
            gi16[((size_t)(t * NBS + pbs) * G_SZ + gr)      * MB + pm] = (f16)(acc0[r] + bias[0][r]);
            gi16[((size_t)(t * NBS + pbs) * G_SZ + gr + 16) * MB + pm] = (f16)(acc1[r] + bias[1][r]);
            gi16[((size_t)(t * NBS + pbs) * G_SZ + gr + 32) * MB + pm] = (f16)(acc2[r] + bias[2][r]);
        }
    }
}

// ---------------------------------------------------------------------------
// Persistent GRU: 64 blocks = 8 clusters x 8 h-slices, SINGLE chain per block
// (R11's per-phase structure minus the serializing second chain). Weights:
// 1 reg tile/wave (16 x half8 = 64 VGPR, proven resident) + 6 tiles in LDS
// (96 KB, XOR-swizzled). R10's 3-phase sentinel-pull protocol, unchanged.
// Halved readers (8/cluster) halve the coherent MALL read traffic per step.
// ---------------------------------------------------------------------------
__global__ __launch_bounds__(NTHR, 1)
void gru_persist(const f16* __restrict__ gi,      // [T][NBS][G][MB] f16
                 const f16* __restrict__ wf16,    // [NHS][GB][512]
                 const float* __restrict__ h0,
                 const float* __restrict__ b_hh,
                 f16* __restrict__ hbuf,          // [NBS][3][16][512] f16
                 float* __restrict__ out) {
    const int bs  = blockIdx.x & (NBS - 1);
    const int hs  = blockIdx.x >> 3;      // 0..7
    const int tid = threadIdx.x;

    __shared__ __align__(16) unsigned char w_lds[96 * 1024];      // 96 KB
    __shared__ __align__(16) unsigned char h_lds[MB * H_SZ * 2];  // 16 KB
    __shared__ float act_r[MB][HB + 1];
    __shared__ float act_z[MB][HB + 1];
    __shared__ float act_n[MB][HB + 1];
    __shared__ float act_i[MB][HB + 1];

    const int wid  = tid >> 6;
    const int lane = tid & 63;
    const int col  = lane & 15;
    const int krow = lane >> 4;

    const int ttR = wid, ttL = wid + 6;
    const int gateR = ttR >> 2, gateL = ttL >> 2;   // R: 0,0,0,0,1,1  L: 1,1,2,2,2,2
    const int gcR = (ttR & 3) * 16 + col;
    const int gcL = (ttL & 3) * 16 + col;
    const int ggR = gateR * H_SZ + hs * HB + gcR;
    const int ggL = gateL * H_SZ + hs * HB + gcL;
    const float biasR = b_hh[ggR];
    const float biasL = b_hh[ggL];

    const f16* wbase = wf16 + (size_t)hs * GB * H_SZ;

    for (int i = tid; i < 96 * 64; i += NTHR) {     // LDS tiles: 6144 x 16B
        int r = i >> 6, k8 = i & 63;
        f32x4 v = *reinterpret_cast<const f32x4*>(
            wbase + (size_t)(96 + r) * H_SZ + k8 * 8);
        unsigned addr = ((unsigned)(r * 1024 + k8 * 16)) ^ (((unsigned)(r & 7)) << 4);
        *reinterpret_cast<f32x4*>(w_lds + addr) = v;
    }
    half8 bfrag[16];   // reg tile: the proven-resident shape
    {
        const f16* wp = wbase + (size_t)(ttR * 16 + col) * H_SZ + krow * 8;
        #pragma unroll
        for (int kk = 0; kk < 16; ++kk)
            bfrag[kk] = *reinterpret_cast<const half8*>(wp + kk * 32);
    }

    const int cb  = tid >> 4;
    const int cc4 = (tid & 15) * 4;
    f32x4 hm = {0.f, 0.f, 0.f, 0.f};
    if (tid < 256) {
        #pragma unroll
        for (int u = 0; u < 4; ++u) hm[u] = h0[hs * HB + cc4 + u];
    }

    const unsigned a_base = (unsigned)(col * 1024 + krow * 16);
    const unsigned a_swz  = ((unsigned)(col & 7)) << 4;
    const unsigned b_base = (unsigned)((wid * 16 + col) * 1024 + krow * 16);

    const int i0 = tid, i1 = tid + NTHR, i2 = tid + 2 * NTHR;
    const bool has2 = (tid < 256);
    const f32x4 sentv = __builtin_bit_cast(f32x4,
        (uint32x4){SENT32, SENT32, SENT32, SENT32});

    f16* hb = hbuf + (size_t)bs * SLC;

    __syncthreads();

    for (int t = 0; t < T_SEQ; ++t) {
        const size_t pcO = (size_t)(t % 3) * PH;
        const size_t pnO = (size_t)((t + 1) % 3) * PH;
        const size_t paO = (size_t)((t + 2) % 3) * PH;

        // gi loads issued first; latency folds into poll wait
        f16x4 gvR = load_f16x4_nw(
            gi + ((size_t)(t * NBS + bs) * G_SZ + ggR) * MB + krow * 4);
        f16x4 gvL = load_f16x4_nw(
            gi + ((size_t)(t * NBS + bs) * G_SZ + ggL) * MB + krow * 4);

        // ---- poll phase-pc granules until sentinel-free ----
        const f16* hin = hb + pcO;
        const f16* a0p = hin + (i0 >> 6) * H_SZ + (i0 & 63) * 8;
        const f16* a1p = hin + (i1 >> 6) * H_SZ + (i1 & 63) * 8;
        const f16* a2p = hin + (i2 >> 6) * H_SZ + (i2 & 63) * 8;
        f32x4 v0 = cload_f4(a0p);
        f32x4 v1 = cload_f4(a1p);
        f32x4 v2;
        if (has2) v2 = cload_f4(a2p);
        wait_vm0();
        {
            int guard = 0;
            bool s0 = stale4(v0), s1 = stale4(v1), s2 = has2 && stale4(v2);
            while (__any(s0 | s1 | s2)) {
                if (s0) v0 = cload_f4((const void*)a0p);
                if (s1) v1 = cload_f4((const void*)a1p);
                if (s2) v2 = cload_f4((const void*)a2p);
                wait_vm0();
                s0 = stale4(v0); s1 = stale4(v1); s2 = has2 && stale4(v2);
                if (++guard > (1 << 20)) break;   // safety valve
            }
        }

        // ---- stage to LDS (swizzled); arm own cols of phase pa ----
        {
            unsigned l0 = ((unsigned)((i0 >> 6) * 1024 + (i0 & 63) * 16))
                          ^ (((unsigned)((i0 >> 6) & 7)) << 4);
            *reinterpret_cast<f32x4*>(h_lds + l0) = v0;
            unsigned l1 = ((unsigned)((i1 >> 6) * 1024 + (i1 & 63) * 16))
                          ^ (((unsigned)((i1 >> 6) & 7)) << 4);
            *reinterpret_cast<f32x4*>(h_lds + l1) = v1;
            if (has2) {
                unsigned l2 = ((unsigned)((i2 >> 6) * 1024 + (i2 & 63) * 16))
                              ^ (((unsigned)((i2 >> 6) & 7)) << 4);
                *reinterpret_cast<f32x4*>(h_lds + l2) = v2;
            }
            if (tid < 128) {   // our 128 granules: 16 rows x 8 granules (64 cols)
                int row = tid >> 3, g = tid & 7;
                cstore_f4(hb + paO + (size_t)row * H_SZ + hs * HB + g * 8, sentv);
            }
        }
        __syncthreads();

        // ---- gh: 16 batch x 32 cols/wave, K=512 (reg tile + LDS tile) ----
        f32x4 accR = {0.f,0.f,0.f,0.f}, accL = {0.f,0.f,0.f,0.f};
        #pragma unroll
        for (int kk = 0; kk < 16; ++kk) {
            half8 av = *reinterpret_cast<const half8*>(
                h_lds + ((a_base + kk * 64) ^ a_swz));
            half8 bv = *reinterpret_cast<const half8*>(
                w_lds + ((b_base + kk * 64) ^ a_swz));
            accR = __builtin_amdgcn_mfma_f32_16x16x32_f16(av, bfrag[kk], accR, 0, 0, 0);
            accL = __builtin_amdgcn_mfma_f32_16x16x32_f16(av, bv,        accL, 0, 0, 0);
        }
        wait_vm0();   // arm stores + gi retired (hidden under MFMA) [protocol-critical]

        // ---- raw pre-activations to LDS; combine applies nonlinearity ----
        if (gateR == 0) {
            #pragma unroll
            for (int r = 0; r < 4; ++r)
                act_r[krow * 4 + r][gcR] = accR[r] + biasR + (float)gvR[r];
        } else {
            #pragma unroll
            for (int r = 0; r < 4; ++r)
                act_z[krow * 4 + r][gcR] = accR[r] + biasR + (float)gvR[r];
        }
        if (gateL == 1) {
            #pragma unroll
            for (int r = 0; r < 4; ++r)
                act_z[krow * 4 + r][gcL] = accL[r] + biasL + (float)gvL[r];
        } else {
            #pragma unroll
            for (int r = 0; r < 4; ++r) {
                act_n[krow * 4 + r][gcL] = accL[r] + biasL;
                act_i[krow * 4 + r][gcL] = (float)gvL[r];
            }
        }
        __syncthreads();

        // ---- combine (tid<256): 1 batch x 4 cols; publish once ----
        if (tid < 256) {
            float h4[4];
            unsigned short us[4];
            #pragma unroll
            for (int u = 0; u < 4; ++u) {
                int c = cc4 + u;
                float r = 1.f / (1.f + __expf(-act_r[cb][c]));
                float z = 1.f / (1.f + __expf(-act_z[cb][c]));
                float a = act_i[cb][c] + r * act_n[cb][c];
                float n = 1.f - 2.f / (__expf(2.f * a) + 1.f);
                float hn = (1.f - z) * n + z * hm[u];
                hn = fminf(fmaxf(hn, -5.f), 5.f);
                hm[u] = hn;
                h4[u] = hn;
                us[u] = __builtin_bit_cast(unsigned short, (f16)hn);
            }
            uint32x2 pk;
            pk[0] = (unsigned)us[0] | ((unsigned)us[1] << 16);
            pk[1] = (unsigned)us[2] | ((unsigned)us[3] << 16);
            const int hg = hs * HB + cc4;
            cstore_u2(hb + pnO + (size_t)cb * H_SZ + hg, pk);   // the publish

            const int bg = bs * MB + cb;
            *reinterpret_cast<float4*>(
                out + ((size_t)bg * T_SEQ + t) * H_SZ + hg) =
                make_float4(h4[0], h4[1], h4[2], h4[3]);
            if (t == T_SEQ - 1)
                *reinterpret_cast<float4*>(
                    out + (size_t)B_SZ * T_SEQ * H_SZ + (size_t)bg * H_SZ + hg) =
                    make_float4(h4[0], h4[1], h4[2], h4[3]);
        }
        // no drain, no flag, no barrier: next step's poll is the sync.
    }
}

// ---------------------------------------------------------------------------
extern "C" void kernel_launch(void* const* d_in, const int* in_sizes, int n_in,
                              void* d_out, int out_size, void* d_ws, size_t ws_size,
                              hipStream_t stream) {
    const float* x    = (const float*)d_in[0];
    const float* h0   = (const float*)d_in[1];
    const float* w_ih = (const float*)d_in[2];
    const float* w_hh = (const float*)d_in[3];
    const float* b_ih = (const float*)d_in[4];
    const float* b_hh = (const float*)d_in[5];
    float* out = (float*)d_out;

    char* p = (char*)d_ws;
    f16* wp16 = (f16*)p;   p += (size_t)I_SZ * G_SZ * 2;            // 768 KB
    f16* wf16 = (f16*)p;   p += (size_t)NHS * GB * H_SZ * 2;        // 1.5 MB
    f16* hbuf = (f16*)p;   p += (size_t)NBS * SLC * 2;              // 384 KB
    f16* gi   = (f16*)p;   // [T][NBS][G][MB] f16 = 402 MB (ws >= 810 MB proven)

    setup_kernel<<<512, 256, 0, stream>>>(w_ih, w_hh, h0, wp16, wf16, hbuf);

    proj_kernel<<<T_SEQ * 4, 512, 0, stream>>>(x, wp16, b_ih, gi);

    gru_persist<<<NBS * NHS, NTHR, 0, stream>>>(gi, wf16, h0, b_hh, hbuf, out);
}

// Round 13
// 2997.979 us; speedup vs baseline: 1.6342x; 1.0626x over previous
//
#include <hip/hip_runtime.h>
#include <math.h>

#define T_SEQ 1024
#define B_SZ  128
#define I_SZ  256
#define H_SZ  512
#define G_SZ  1536  // 3*H

#define NBS   8     // batch slices (clusters)
#define MB    16    // batch per slice
#define NHS   8     // h slices = blocks per cluster
#define HB    64    // h cols per block
#define GB    192   // gate cols per block (3*HB)
#define NTHR  384   // 6 waves
#define PGB   384   // proj: gate cols per block
#define PH    (MB * H_SZ)      // one (t,bs) region: 8192 f16 (16 KB)

#define SENT32 0x7FFF7FFFu  // two f16 NaNs; h clipped to +-5 so never legit

typedef _Float16 f16;
typedef _Float16 half8 __attribute__((ext_vector_type(8)));
typedef _Float16 f16x4 __attribute__((ext_vector_type(4)));
typedef float f32x4 __attribute__((ext_vector_type(4)));
typedef unsigned uint32x2 __attribute__((ext_vector_type(2)));
typedef unsigned uint32x4 __attribute__((ext_vector_type(4)));

// ---- MALL-coherent (sc0 sc1) ops: bypass L1/L2; device-wide coherent ----
__device__ __forceinline__ f32x4 cload_f4(const void* p) {
    f32x4 v;
    asm volatile("global_load_dwordx4 %0, %1, off sc0 sc1" : "=v"(v) : "v"(p));
    return v;
}
__device__ __forceinline__ void cstore_u2(void* p, uint32x2 v) {
    asm volatile("global_store_dwordx2 %0, %1, off sc0 sc1" :: "v"(p), "v"(v) : "memory");
}
__device__ __forceinline__ f16x4 load_f16x4_nw(const void* p) {
    f16x4 v;
    asm volatile("global_load_dwordx2 %0, %1, off" : "=v"(v) : "v"(p));
    return v;
}
__device__ __forceinline__ void wait_vm0() {
    asm volatile("s_waitcnt vmcnt(0)" ::: "memory");
    __builtin_amdgcn_sched_barrier(0);
}
__device__ __forceinline__ bool stale4(f32x4 v) {
    uint32x4 u = __builtin_bit_cast(uint32x4, v);
    return (u[0] == SENT32) | (u[1] == SENT32) | (u[2] == SENT32) | (u[3] == SENT32);
}

// ---------------------------------------------------------------------------
// Setup: w_ih -> f16 [g][i]; w_hh -> f16 slices [hs=8][GB=192][512]
// (gl<96 = register tiles, gl>=96 = LDS tiles); hbuf[(T+1)][NBS][16][512]:
// region 0 <- h0 broadcast, regions 1..T <- sentinel (vectorized).
// ---------------------------------------------------------------------------
__global__ void setup_kernel(const float* __restrict__ w_ih,
                             const float* __restrict__ w_hh,
                             const float* __restrict__ h0,
                             f16* __restrict__ wp16,
                             f16* __restrict__ wf16,
                             f16* __restrict__ hbuf) {
    const size_t i0 = (size_t)blockIdx.x * blockDim.x + threadIdx.x;
    const size_t stride = (size_t)gridDim.x * blockDim.x;
    for (size_t i = i0; i < (size_t)I_SZ * G_SZ; i += stride)
        wp16[i] = (f16)w_ih[i];
    for (size_t i = i0; i < (size_t)NHS * GB * H_SZ; i += stride) {
        int hs  = (int)(i / (GB * H_SZ));
        int rem = (int)(i % (GB * H_SZ));
        int gl = rem / H_SZ, k = rem % H_SZ;
        int gate = gl >> 6, c = gl & 63;
        int gg = gate * H_SZ + hs * HB + c;
        wf16[i] = (f16)w_hh[(size_t)gg * H_SZ + k];
    }
    // region 0: h0 broadcast over [bs][m][h]
    for (size_t i = i0; i < (size_t)NBS * PH; i += stride)
        hbuf[i] = (f16)h0[i & (H_SZ - 1)];
    // regions 1..T: sentinel, 16 B per store
    const uint32x4 sv = {SENT32, SENT32, SENT32, SENT32};
    const size_t base = (size_t)NBS * PH;                 // start of region 1
    const size_t nv   = (size_t)T_SEQ * NBS * PH / 8;     // 8 f16 per store
    for (size_t i = i0; i < nv; i += stride)
        *reinterpret_cast<uint32x4*>(hbuf + base + i * 8) = sv;
}

// ---------------------------------------------------------------------------
// Input projection, f16 MFMA (passed R7/R9/R10/R11/R12, unchanged). Dense gi:
// gi16[((t*NBS + bs)*G + g)*MB + m],  bs = b>>4, m = b&15.
// ---------------------------------------------------------------------------
__global__ __launch_bounds__(512, 1)
void proj_kernel(const float* __restrict__ x,
                 const f16* __restrict__ wp16,
                 const float* __restrict__ b_ih,
                 f16* __restrict__ gi16) {
    const int t  = blockIdx.x >> 2;
    const int g0 = (blockIdx.x & 3) * PGB;
    const int tid  = threadIdx.x;
    const int wid  = tid >> 6;
    const int lane = tid & 63;
    const int col  = lane & 15;
    const int krow = lane >> 4;

    __shared__ __align__(16) unsigned char x_lds[128 * 512];  // [b][k] f16, 64 KB

    #pragma unroll
    for (int j = 0; j < 8; ++j) {
        int idx = tid + j * 512;
        int b = idx >> 5, k16 = idx & 31;
        const float* xp = x + ((size_t)b * T_SEQ + t) * I_SZ + k16 * 8;
        float4 v0 = *reinterpret_cast<const float4*>(xp);
        float4 v1 = *reinterpret_cast<const float4*>(xp + 4);
        half8 hv;
        hv[0] = (f16)v0.x; hv[1] = (f16)v0.y; hv[2] = (f16)v0.z; hv[3] = (f16)v0.w;
        hv[4] = (f16)v1.x; hv[5] = (f16)v1.y; hv[6] = (f16)v1.z; hv[7] = (f16)v1.w;
        unsigned addr = ((unsigned)(b * 512 + k16 * 16)) ^ (((unsigned)(b & 7)) << 4);
        *reinterpret_cast<half8*>(x_lds + addr) = hv;
    }

    const int gw0 = g0 + wid * 48;
    half8 af[3][8];
    #pragma unroll
    for (int m = 0; m < 3; ++m)
        #pragma unroll
        for (int k = 0; k < 8; ++k)
            af[m][k] = *reinterpret_cast<const half8*>(
                wp16 + (size_t)(gw0 + m * 16 + col) * I_SZ + k * 32 + krow * 8);

    float bias[3][4];
    #pragma unroll
    for (int m = 0; m < 3; ++m)
        #pragma unroll
        for (int r = 0; r < 4; ++r)
            bias[m][r] = b_ih[gw0 + m * 16 + krow * 4 + r];

    __syncthreads();

    #pragma unroll
    for (int nt = 0; nt < 8; ++nt) {
        const int b0 = nt * 16;
        f32x4 acc0 = {0.f,0.f,0.f,0.f}, acc1 = {0.f,0.f,0.f,0.f}, acc2 = {0.f,0.f,0.f,0.f};
        const int brow = b0 + col;
        const unsigned bswz = ((unsigned)(brow & 7)) << 4;
        #pragma unroll
        for (int k = 0; k < 8; ++k) {
            half8 bf = *reinterpret_cast<const half8*>(
                x_lds + (((unsigned)(brow * 512 + k * 64 + krow * 16)) ^ bswz));
            acc0 = __builtin_amdgcn_mfma_f32_16x16x32_f16(af[0][k], bf, acc0, 0, 0, 0);
            acc1 = __builtin_amdgcn_mfma_f32_16x16x32_f16(af[1][k], bf, acc1, 0, 0, 0);
            acc2 = __builtin_amdgcn_mfma_f32_16x16x32_f16(af[2][k], bf, acc2, 0, 0, 0);
        }
        const int pbs = brow >> 4;
        const int pm  = brow & 15;
        #pragma unroll
        for (int r = 0; r < 4; ++r) {
            int gr = gw0 + krow * 4 + r;
            gi16[((size_t)(t * NBS + pbs) * G_SZ + gr)      * MB + pm] = (f16)(acc0[r] + bias[0][r]);
            gi16[((size_t)(t * NBS + pbs) * G_SZ + gr + 16) * MB + pm] = (f16)(acc1[r] + bias[1][r]);
            gi16[((size_t)(t * NBS + pbs) * G_SZ + gr + 32) * MB + pm] = (f16)(acc2[r] + bias[2][r]);
        }
    }
}

// ---------------------------------------------------------------------------
// Persistent GRU: 64 blocks = 8 clusters x 8 h-slices (R12 geometry/weights:
// 1 reg tile/wave + 6 tiles in LDS). T-region no-arm protocol: step t polls
// region t (pre-sentineled at setup, written once by step t-1's publishes),
// publishes h_{t+1} to region t+1. No arm stores, no region reuse. s_sleep(8)
// before poll issue delays the first MALL sample past the publish-visibility
// window, eliminating the once-per-step retry round-trip.
// ---------------------------------------------------------------------------
__global__ __launch_bounds__(NTHR, 1)
void gru_persist(const f16* __restrict__ gi,      // [T][NBS][G][MB] f16
                 const f16* __restrict__ wf16,    // [NHS][GB][512]
                 const float* __restrict__ h0,
                 const float* __restrict__ b_hh,
                 f16* __restrict__ hbuf,          // [(T+1)][NBS][16][512] f16
                 float* __restrict__ out) {
    const int bs  = blockIdx.x & (NBS - 1);
    const int hs  = blockIdx.x >> 3;      // 0..7
    const int tid = threadIdx.x;

    __shared__ __align__(16) unsigned char w_lds[96 * 1024];      // 96 KB
    __shared__ __align__(16) unsigned char h_lds[MB * H_SZ * 2];  // 16 KB
    __shared__ float act_r[MB][HB + 1];
    __shared__ float act_z[MB][HB + 1];
    __shared__ float act_n[MB][HB + 1];
    __shared__ float act_i[MB][HB + 1];

    const int wid  = tid >> 6;
    const int lane = tid & 63;
    const int col  = lane & 15;
    const int krow = lane >> 4;

    const int ttR = wid, ttL = wid + 6;
    const int gateR = ttR >> 2, gateL = ttL >> 2;   // R: 0,0,0,0,1,1  L: 1,1,2,2,2,2
    const int gcR = (ttR & 3) * 16 + col;
    const int gcL = (ttL & 3) * 16 + col;
    const int ggR = gateR * H_SZ + hs * HB + gcR;
    const int ggL = gateL * H_SZ + hs * HB + gcL;
    const float biasR = b_hh[ggR];
    const float biasL = b_hh[ggL];

    const f16* wbase = wf16 + (size_t)hs * GB * H_SZ;

    for (int i = tid; i < 96 * 64; i += NTHR) {     // LDS tiles: 6144 x 16B
        int r = i >> 6, k8 = i & 63;
        f32x4 v = *reinterpret_cast<const f32x4*>(
            wbase + (size_t)(96 + r) * H_SZ + k8 * 8);
        unsigned addr = ((unsigned)(r * 1024 + k8 * 16)) ^ (((unsigned)(r & 7)) << 4);
        *reinterpret_cast<f32x4*>(w_lds + addr) = v;
    }
    half8 bfrag[16];   // reg tile: the proven-resident shape
    {
        const f16* wp = wbase + (size_t)(ttR * 16 + col) * H_SZ + krow * 8;
        #pragma unroll
        for (int kk = 0; kk < 16; ++kk)
            bfrag[kk] = *reinterpret_cast<const half8*>(wp + kk * 32);
    }

    const int cb  = tid >> 4;
    const int cc4 = (tid & 15) * 4;
    f32x4 hm = {0.f, 0.f, 0.f, 0.f};
    if (tid < 256) {
        #pragma unroll
        for (int u = 0; u < 4; ++u) hm[u] = h0[hs * HB + cc4 + u];
    }

    const unsigned a_base = (unsigned)(col * 1024 + krow * 16);
    const unsigned a_swz  = ((unsigned)(col & 7)) << 4;
    const unsigned b_base = (unsigned)((wid * 16 + col) * 1024 + krow * 16);

    const int i0 = tid, i1 = tid + NTHR, i2 = tid + 2 * NTHR;
    const bool has2 = (tid < 256);

    __syncthreads();

    for (int t = 0; t < T_SEQ; ++t) {
        const f16* hin  = hbuf + ((size_t)t       * NBS + bs) * PH;  // consume
        f16*       hpub = hbuf + ((size_t)(t + 1) * NBS + bs) * PH;  // produce

        // gi loads issued first (plain); latency folds into poll wait
        f16x4 gvR = load_f16x4_nw(
            gi + ((size_t)(t * NBS + bs) * G_SZ + ggR) * MB + krow * 4);
        f16x4 gvL = load_f16x4_nw(
            gi + ((size_t)(t * NBS + bs) * G_SZ + ggL) * MB + krow * 4);

        // delay the first poll sample past the publish-visibility window
        __builtin_amdgcn_s_sleep(8);

        // ---- poll region-t granules until sentinel-free ----
        const f16* a0p = hin + (i0 >> 6) * H_SZ + (i0 & 63) * 8;
        const f16* a1p = hin + (i1 >> 6) * H_SZ + (i1 & 63) * 8;
        const f16* a2p = hin + (i2 >> 6) * H_SZ + (i2 & 63) * 8;
        f32x4 v0 = cload_f4(a0p);
        f32x4 v1 = cload_f4(a1p);
        f32x4 v2;
        if (has2) v2 = cload_f4(a2p);
        wait_vm0();
        {
            int guard = 0;
            bool s0 = stale4(v0), s1 = stale4(v1), s2 = has2 && stale4(v2);
            while (__any(s0 | s1 | s2)) {
                if (s0) v0 = cload_f4((const void*)a0p);
                if (s1) v1 = cload_f4((const void*)a1p);
                if (s2) v2 = cload_f4((const void*)a2p);
                wait_vm0();
                s0 = stale4(v0); s1 = stale4(v1); s2 = has2 && stale4(v2);
                if (++guard > (1 << 20)) break;   // safety valve
            }
        }

        // ---- stage to LDS (swizzled); no arm stores (T-region protocol) ----
        {
            unsigned l0 = ((unsigned)((i0 >> 6) * 1024 + (i0 & 63) * 16))
                          ^ (((unsigned)((i0 >> 6) & 7)) << 4);
            *reinterpret_cast<f32x4*>(h_lds + l0) = v0;
            unsigned l1 = ((unsigned)((i1 >> 6) * 1024 + (i1 & 63) * 16))
                          ^ (((unsigned)((i1 >> 6) & 7)) << 4);
            *reinterpret_cast<f32x4*>(h_lds + l1) = v1;
            if (has2) {
                unsigned l2 = ((unsigned)((i2 >> 6) * 1024 + (i2 & 63) * 16))
                              ^ (((unsigned)((i2 >> 6) & 7)) << 4);
                *reinterpret_cast<f32x4*>(h_lds + l2) = v2;
            }
        }
        __syncthreads();

        // ---- gh: 16 batch x 32 cols/wave, K=512 (reg tile + LDS tile) ----
        f32x4 accR = {0.f,0.f,0.f,0.f}, accL = {0.f,0.f,0.f,0.f};
        #pragma unroll
        for (int kk = 0; kk < 16; ++kk) {
            half8 av = *reinterpret_cast<const half8*>(
                h_lds + ((a_base + kk * 64) ^ a_swz));
            half8 bv = *reinterpret_cast<const half8*>(
                w_lds + ((b_base + kk * 64) ^ a_swz));
            accR = __builtin_amdgcn_mfma_f32_16x16x32_f16(av, bfrag[kk], accR, 0, 0, 0);
            accL = __builtin_amdgcn_mfma_f32_16x16x32_f16(av, bv,        accL, 0, 0, 0);
        }
        wait_vm0();   // gi resident before activations (normally already arrived)

        // ---- raw pre-activations to LDS; combine applies nonlinearity ----
        if (gateR == 0) {
            #pragma unroll
            for (int r = 0; r < 4; ++r)
                act_r[krow * 4 + r][gcR] = accR[r] + biasR + (float)gvR[r];
        } else {
            #pragma unroll
            for (int r = 0; r < 4; ++r)
                act_z[krow * 4 + r][gcR] = accR[r] + biasR + (float)gvR[r];
        }
        if (gateL == 1) {
            #pragma unroll
            for (int r = 0; r < 4; ++r)
                act_z[krow * 4 + r][gcL] = accL[r] + biasL + (float)gvL[r];
        } else {
            #pragma unroll
            for (int r = 0; r < 4; ++r) {
                act_n[krow * 4 + r][gcL] = accL[r] + biasL;
                act_i[krow * 4 + r][gcL] = (float)gvL[r];
            }
        }
        __syncthreads();

        // ---- combine (tid<256): 1 batch x 4 cols; publish once ----
        if (tid < 256) {
            float h4[4];
            unsigned short us[4];
            #pragma unroll
            for (int u = 0; u < 4; ++u) {
                int c = cc4 + u;
                float r = 1.f / (1.f + __expf(-act_r[cb][c]));
                float z = 1.f / (1.f + __expf(-act_z[cb][c]));
                float a = act_i[cb][c] + r * act_n[cb][c];
                float n = 1.f - 2.f / (__expf(2.f * a) + 1.f);
                float hn = (1.f - z) * n + z * hm[u];
                hn = fminf(fmaxf(hn, -5.f), 5.f);
                hm[u] = hn;
                h4[u] = hn;
                us[u] = __builtin_bit_cast(unsigned short, (f16)hn);
            }
            uint32x2 pk;
            pk[0] = (unsigned)us[0] | ((unsigned)us[1] << 16);
            pk[1] = (unsigned)us[2] | ((unsigned)us[3] << 16);
            const int hg = hs * HB + cc4;
            cstore_u2(hpub + (size_t)cb * H_SZ + hg, pk);   // the publish

            const int bg = bs * MB + cb;
            *reinterpret_cast<float4*>(
                out + ((size_t)bg * T_SEQ + t) * H_SZ + hg) =
                make_float4(h4[0], h4[1], h4[2], h4[3]);
            if (t == T_SEQ - 1)
                *reinterpret_cast<float4*>(
                    out + (size_t)B_SZ * T_SEQ * H_SZ + (size_t)bg * H_SZ + hg) =
                    make_float4(h4[0], h4[1], h4[2], h4[3]);
        }
        // no drain, no flag, no barrier: next step's poll is the sync.
    }
}

// ---------------------------------------------------------------------------
extern "C" void kernel_launch(void* const* d_in, const int* in_sizes, int n_in,
                              void* d_out, int out_size, void* d_ws, size_t ws_size,
                              hipStream_t stream) {
    const float* x    = (const float*)d_in[0];
    const float* h0   = (const float*)d_in[1];
    const float* w_ih = (const float*)d_in[2];
    const float* w_hh = (const float*)d_in[3];
    const float* b_ih = (const float*)d_in[4];
    const float* b_hh = (const float*)d_in[5];
    float* out = (float*)d_out;

    char* p = (char*)d_ws;
    f16* wp16 = (f16*)p;   p += (size_t)I_SZ * G_SZ * 2;                 // 768 KB
    f16* wf16 = (f16*)p;   p += (size_t)NHS * GB * H_SZ * 2;             // 1.5 MB
    f16* hbuf = (f16*)p;   p += (size_t)(T_SEQ + 1) * NBS * PH * 2;      // 134 MB
    f16* gi   = (f16*)p;   // [T][NBS][G][MB] f16 = 402 MB (ws >= 808 MB proven)

    setup_kernel<<<2048, 256, 0, stream>>>(w_ih, w_hh, h0, wp16, wf16, hbuf);

    proj_kernel<<<T_SEQ * 4, 512, 0, stream>>>(x, wp16, b_ih, gi);

    gru_persist<<<NBS * NHS, NTHR, 0, stream>>>(gi, wf16, h0, b_hh, hbuf, out);
}

// Round 14
// 2959.855 us; speedup vs baseline: 1.6552x; 1.0129x over previous
//
#include <hip/hip_runtime.h>
#include <math.h>

#define T_SEQ 1024
#define B_SZ  128
#define I_SZ  256
#define H_SZ  512
#define G_SZ  1536  // 3*H

#define NBS   8     // batch slices (clusters)
#define MB    16    // batch per slice
#define NHS   8     // h slices = blocks per cluster
#define HB    64    // h cols per block
#define GB    192   // gate cols per block (3*HB)
#define GNTHR 256   // gru threads: 4 waves, one 16-col tile each
#define PGB   384   // proj: gate cols per block
#define PH    (MB * H_SZ)      // one (t,bs) region: 8192 f16 (16 KB)

#define SENTU16 0x7FFFu  // f16 NaN; h clipped to +-5 so never legit

typedef _Float16 f16;
typedef _Float16 half8 __attribute__((ext_vector_type(8)));
typedef _Float16 f16x4 __attribute__((ext_vector_type(4)));
typedef float f32x4 __attribute__((ext_vector_type(4)));
typedef unsigned uint32x4 __attribute__((ext_vector_type(4)));

// ---- MALL-coherent (sc0 sc1) ops: bypass L1/L2; device-wide coherent ----
__device__ __forceinline__ f32x4 cload_f4(const void* p) {
    f32x4 v;
    asm volatile("global_load_dwordx4 %0, %1, off sc0 sc1" : "=v"(v) : "v"(p));
    return v;
}
__device__ __forceinline__ void cstore_u16(void* p, unsigned v) {
    asm volatile("global_store_short %0, %1, off sc0 sc1" :: "v"(p), "v"(v) : "memory");
}
__device__ __forceinline__ f16x4 load_f16x4_nw(const void* p) {
    f16x4 v;
    asm volatile("global_load_dwordx2 %0, %1, off" : "=v"(v) : "v"(p));
    return v;
}
__device__ __forceinline__ void wait_vm0() {
    asm volatile("s_waitcnt vmcnt(0)" ::: "memory");
    __builtin_amdgcn_sched_barrier(0);
}
// per-u16 sentinel check: publishes are 2-B stores, so a dword may be
// half-written; any u16 == 0x7FFF means stale/incomplete.
__device__ __forceinline__ bool stale4(f32x4 v) {
    uint32x4 u = __builtin_bit_cast(uint32x4, v);
    bool s = false;
    #pragma unroll
    for (int i = 0; i < 4; ++i) {
        s |= ((u[i] & 0xFFFFu) == SENTU16);
        s |= ((u[i] >> 16)     == SENTU16);
    }
    return s;
}

// ---------------------------------------------------------------------------
// Setup (R13 verbatim): w_ih -> f16 [g][i]; w_hh -> f16 slices [hs=8][192][512]
// (gl<64 = r/reg tiles, 64..191 = z,n/LDS tiles); hbuf[(T+1)][NBS][16][512]:
// region 0 <- h0 broadcast, regions 1..T <- sentinel.
// ---------------------------------------------------------------------------
__global__ void setup_kernel(const float* __restrict__ w_ih,
                             const float* __restrict__ w_hh,
                             const float* __restrict__ h0,
                             f16* __restrict__ wp16,
                             f16* __restrict__ wf16,
                             f16* __restrict__ hbuf) {
    const size_t i0 = (size_t)blockIdx.x * blockDim.x + threadIdx.x;
    const size_t stride = (size_t)gridDim.x * blockDim.x;
    for (size_t i = i0; i < (size_t)I_SZ * G_SZ; i += stride)
        wp16[i] = (f16)w_ih[i];
    for (size_t i = i0; i < (size_t)NHS * GB * H_SZ; i += stride) {
        int hs  = (int)(i / (GB * H_SZ));
        int rem = (int)(i % (GB * H_SZ));
        int gl = rem / H_SZ, k = rem % H_SZ;
        int gate = gl >> 6, c = gl & 63;
        int gg = gate * H_SZ + hs * HB + c;
        wf16[i] = (f16)w_hh[(size_t)gg * H_SZ + k];
    }
    for (size_t i = i0; i < (size_t)NBS * PH; i += stride)
        hbuf[i] = (f16)h0[i & (H_SZ - 1)];
    const uint32x4 sv = {0x7FFF7FFFu, 0x7FFF7FFFu, 0x7FFF7FFFu, 0x7FFF7FFFu};
    const size_t base = (size_t)NBS * PH;
    const size_t nv   = (size_t)T_SEQ * NBS * PH / 8;
    for (size_t i = i0; i < nv; i += stride)
        *reinterpret_cast<uint32x4*>(hbuf + base + i * 8) = sv;
}

// ---------------------------------------------------------------------------
// Input projection, f16 MFMA (passed R7-R13, unchanged). Dense gi layout:
// gi16[((t*NBS + bs)*G + g)*MB + m],  bs = b>>4, m = b&15.
// ---------------------------------------------------------------------------
__global__ __launch_bounds__(512, 1)
void proj_kernel(const float* __restrict__ x,
                 const f16* __restrict__ wp16,
                 const float* __restrict__ b_ih,
                 f16* __restrict__ gi16) {
    const int t  = blockIdx.x >> 2;
    const int g0 = (blockIdx.x & 3) * PGB;
    const int tid  = threadIdx.x;
    const int wid  = tid >> 6;
    const int lane = tid & 63;
    const int col  = lane & 15;
    const int krow = lane >> 4;

    __shared__ __align__(16) unsigned char x_lds[128 * 512];  // [b][k] f16, 64 KB

    #pragma unroll
    for (int j = 0; j < 8; ++j) {
        int idx = tid + j * 512;
        int b = idx >> 5, k16 = idx & 31;
        const float* xp = x + ((size_t)b * T_SEQ + t) * I_SZ + k16 * 8;
        float4 v0 = *reinterpret_cast<const float4*>(xp);
        float4 v1 = *reinterpret_cast<const float4*>(xp + 4);
        half8 hv;
        hv[0] = (f16)v0.x; hv[1] = (f16)v0.y; hv[2] = (f16)v0.z; hv[3] = (f16)v0.w;
        hv[4] = (f16)v1.x; hv[5] = (f16)v1.y; hv[6] = (f16)v1.z; hv[7] = (f16)v1.w;
        unsigned addr = ((unsigned)(b * 512 + k16 * 16)) ^ (((unsigned)(b & 7)) << 4);
        *reinterpret_cast<half8*>(x_lds + addr) = hv;
    }

    const int gw0 = g0 + wid * 48;
    half8 af[3][8];
    #pragma unroll
    for (int m = 0; m < 3; ++m)
        #pragma unroll
        for (int k = 0; k < 8; ++k)
            af[m][k] = *reinterpret_cast<const half8*>(
                wp16 + (size_t)(gw0 + m * 16 + col) * I_SZ + k * 32 + krow * 8);

    float bias[3][4];
    #pragma unroll
    for (int m = 0; m < 3; ++m)
        #pragma unroll
        for (int r = 0; r < 4; ++r)
            bias[m][r] = b_ih[gw0 + m * 16 + krow * 4 + r];

    __syncthreads();

    #pragma unroll
    for (int nt = 0; nt < 8; ++nt) {
        const int b0 = nt * 16;
        f32x4 acc0 = {0.f,0.f,0.f,0.f}, acc1 = {0.f,0.f,0.f,0.f}, acc2 = {0.f,0.f,0.f,0.f};
        const int brow = b0 + col;
        const unsigned bswz = ((unsigned)(brow & 7)) << 4;
        #pragma unroll
        for (int k = 0; k < 8; ++k) {
            half8 bf = *reinterpret_cast<const half8*>(
                x_lds + (((unsigned)(brow * 512 + k * 64 + krow * 16)) ^ bswz));
            acc0 = __builtin_amdgcn_mfma_f32_16x16x32_f16(af[0][k], bf, acc0, 0, 0, 0);
            acc1 = __builtin_amdgcn_mfma_f32_16x16x32_f16(af[1][k], bf, acc1, 0, 0, 0);
            acc2 = __builtin_amdgcn_mfma_f32_16x16x32_f16(af[2][k], bf, acc2, 0, 0, 0);
        }
        const int pbs = brow >> 4;
        const int pm  = brow & 15;
        #pragma unroll
        for (int r = 0; r < 4; ++r) {
            int gr = gw0 + krow * 4 + r;
            gi16[((size_t)(t * NBS + pbs) * G_SZ + gr)      * MB + pm] = (f16)(acc0[r] + bias[0][r]);
            gi16[((size_t)(t * NBS + pbs) * G_SZ + gr + 16) * MB + pm] = (f16)(acc1[r] + bias[1][r]);
            gi16[((size_t)(t * NBS + pbs) * G_SZ + gr + 32) * MB + pm] = (f16)(acc2[r] + bias[2][r]);
        }
    }
}

// ---------------------------------------------------------------------------
// Persistent GRU: 64 blocks = 8 clusters x 8 h-slices, 4 waves x 256 thr.
// One wave = one 16-col tile x ALL 3 gates (r from registers, z/n from LDS).
// Combine + publish fully in-register -> no act arrays, ONE barrier per step
// (stage->MFMA). End-of-step ordering is enforced by the poll itself: every
// wave's poll granules span all 64 cols, so no wave can stage step t+1 before
// all waves of its cluster published step t (= finished reading h_lds).
// T-region no-arm protocol (R13), per-u16 sentinel (2-B publishes).
// ---------------------------------------------------------------------------
__global__ __launch_bounds__(GNTHR, 1)
void gru_persist(const f16* __restrict__ gi,      // [T][NBS][G][MB] f16
                 const f16* __restrict__ wf16,    // [NHS][GB][512]
                 const float* __restrict__ h0,
                 const float* __restrict__ b_hh,
                 f16* __restrict__ hbuf,          // [(T+1)][NBS][16][512] f16
                 float* __restrict__ out) {
    const int bs  = blockIdx.x & (NBS - 1);
    const int hs  = blockIdx.x >> 3;      // 0..7
    const int tid = threadIdx.x;

    __shared__ __align__(16) unsigned char w_lds[128 * 1024];     // 128 KB (z,n)
    __shared__ __align__(16) unsigned char h_lds[MB * H_SZ * 2];  // 16 KB

    const int wid  = tid >> 6;
    const int lane = tid & 63;
    const int col  = lane & 15;
    const int krow = lane >> 4;

    const int cg = hs * HB + wid * 16 + col;   // global h-col (0..511)
    const float biasR = b_hh[cg];
    const float biasZ = b_hh[H_SZ + cg];
    const float biasN = b_hh[2 * H_SZ + cg];

    const f16* wbase = wf16 + (size_t)hs * GB * H_SZ;

    // LDS tiles: wf16 rows 64..191 (z: 64..127 -> w_lds rows 0..63,
    //            n: 128..191 -> w_lds rows 64..127), swizzled
    for (int i = tid; i < 128 * 64; i += GNTHR) {   // 8192 x 16B
        int r = i >> 6, k8 = i & 63;
        f32x4 v = *reinterpret_cast<const f32x4*>(
            wbase + (size_t)(64 + r) * H_SZ + k8 * 8);
        unsigned addr = ((unsigned)(r * 1024 + k8 * 16)) ^ (((unsigned)(r & 7)) << 4);
        *reinterpret_cast<f32x4*>(w_lds + addr) = v;
    }
    // reg tile (gate r): the proven-resident 16 x half8 shape
    half8 bfrag[16];
    {
        const f16* wp = wbase + (size_t)(wid * 16 + col) * H_SZ + krow * 8;
        #pragma unroll
        for (int kk = 0; kk < 16; ++kk)
            bfrag[kk] = *reinterpret_cast<const half8*>(wp + kk * 32);
    }

    // running h (f32), 4 batch rows (krow*4+r) x this lane's col
    f32x4 hm;
    {
        float h0v = h0[cg];
        hm[0] = h0v; hm[1] = h0v; hm[2] = h0v; hm[3] = h0v;
    }

    const unsigned a_swz   = ((unsigned)(col & 7)) << 4;
    const unsigned a_base  = (unsigned)(col * 1024 + krow * 16);
    const unsigned bz_base = (unsigned)((wid * 16 + col) * 1024 + krow * 16);
    const unsigned bn_base = (unsigned)((64 + wid * 16 + col) * 1024 + krow * 16);

    // poll granules: k=0..3 -> row wid+4k, col-group = lane (spans ALL cols)
    const int prow0 = wid, prow1 = wid + 4, prow2 = wid + 8, prow3 = wid + 12;

    __syncthreads();

    for (int t = 0; t < T_SEQ; ++t) {
        const f16* hin  = hbuf + ((size_t)t       * NBS + bs) * PH;  // consume
        f16*       hpub = hbuf + ((size_t)(t + 1) * NBS + bs) * PH;  // produce

        // gi loads issued first (plain); drain folds into poll wait
        f16x4 gvR = load_f16x4_nw(
            gi + ((size_t)(t * NBS + bs) * G_SZ + cg) * MB + krow * 4);
        f16x4 gvZ = load_f16x4_nw(
            gi + ((size_t)(t * NBS + bs) * G_SZ + H_SZ + cg) * MB + krow * 4);
        f16x4 gvN = load_f16x4_nw(
            gi + ((size_t)(t * NBS + bs) * G_SZ + 2 * H_SZ + cg) * MB + krow * 4);

        // delay first MALL sample past the publish-visibility window
        __builtin_amdgcn_s_sleep(8);

        // ---- poll region-t granules until sentinel-free (per-u16 check) ----
        const f16* a0p = hin + prow0 * H_SZ + lane * 8;
        const f16* a1p = hin + prow1 * H_SZ + lane * 8;
        const f16* a2p = hin + prow2 * H_SZ + lane * 8;
        const f16* a3p = hin + prow3 * H_SZ + lane * 8;
        f32x4 v0 = cload_f4(a0p);
        f32x4 v1 = cload_f4(a1p);
        f32x4 v2 = cload_f4(a2p);
        f32x4 v3 = cload_f4(a3p);
        wait_vm0();
        {
            int guard = 0;
            bool s0 = stale4(v0), s1 = stale4(v1), s2 = stale4(v2), s3 = stale4(v3);
            while (__any(s0 | s1 | s2 | s3)) {
                if (s0) v0 = cload_f4(a0p);
                if (s1) v1 = cload_f4(a1p);
                if (s2) v2 = cload_f4(a2p);
                if (s3) v3 = cload_f4(a3p);
                wait_vm0();
                s0 = stale4(v0); s1 = stale4(v1); s2 = stale4(v2); s3 = stale4(v3);
                if (++guard > (1 << 20)) break;   // safety valve
            }
        }

        // ---- stage to LDS (swizzled) ----
        {
            unsigned l0 = ((unsigned)(prow0 * 1024 + lane * 16)) ^ (((unsigned)(prow0 & 7)) << 4);
            unsigned l1 = ((unsigned)(prow1 * 1024 + lane * 16)) ^ (((unsigned)(prow1 & 7)) << 4);
            unsigned l2 = ((unsigned)(prow2 * 1024 + lane * 16)) ^ (((unsigned)(prow2 & 7)) << 4);
            unsigned l3 = ((unsigned)(prow3 * 1024 + lane * 16)) ^ (((unsigned)(prow3 & 7)) << 4);
            *reinterpret_cast<f32x4*>(h_lds + l0) = v0;
            *reinterpret_cast<f32x4*>(h_lds + l1) = v1;
            *reinterpret_cast<f32x4*>(h_lds + l2) = v2;
            *reinterpret_cast<f32x4*>(h_lds + l3) = v3;
        }
        __syncthreads();   // the ONE barrier: staged h visible to all waves

        // ---- gh: 16 batch x 16 cols/wave x 3 gates, K=512 ----
        f32x4 accR = {0.f,0.f,0.f,0.f}, accZ = {0.f,0.f,0.f,0.f}, accN = {0.f,0.f,0.f,0.f};
        #pragma unroll
        for (int kk = 0; kk < 16; ++kk) {
            half8 av = *reinterpret_cast<const half8*>(
                h_lds + ((a_base + kk * 64) ^ a_swz));
            half8 bz = *reinterpret_cast<const half8*>(
                w_lds + ((bz_base + kk * 64) ^ a_swz));
            half8 bn = *reinterpret_cast<const half8*>(
                w_lds + ((bn_base + kk * 64) ^ a_swz));
            accR = __builtin_amdgcn_mfma_f32_16x16x32_f16(av, bfrag[kk], accR, 0, 0, 0);
            accZ = __builtin_amdgcn_mfma_f32_16x16x32_f16(av, bz,        accZ, 0, 0, 0);
            accN = __builtin_amdgcn_mfma_f32_16x16x32_f16(av, bn,        accN, 0, 0, 0);
        }

        // ---- in-register combine + publish (no act LDS, no extra barrier) ----
        #pragma unroll
        for (int r = 0; r < 4; ++r) {
            const int b = krow * 4 + r;
            float rr = 1.f / (1.f + __expf(-(accR[r] + biasR + (float)gvR[r])));
            float zz = 1.f / (1.f + __expf(-(accZ[r] + biasZ + (float)gvZ[r])));
            float aa = (float)gvN[r] + rr * (accN[r] + biasN);
            float nn = 1.f - 2.f / (__expf(2.f * aa) + 1.f);
            float hn = (1.f - zz) * nn + zz * hm[r];
            hn = fminf(fmaxf(hn, -5.f), 5.f);
            hm[r] = hn;

            unsigned us = (unsigned)__builtin_bit_cast(unsigned short, (f16)hn);
            cstore_u16(hpub + (size_t)b * H_SZ + cg, us);   // the publish

            const int bg = bs * MB + b;
            out[((size_t)bg * T_SEQ + t) * H_SZ + cg] = hn;
            if (t == T_SEQ - 1)
                out[(size_t)B_SZ * T_SEQ * H_SZ + (size_t)bg * H_SZ + cg] = hn;
        }
        // no drain, no flag, no end barrier: next step's poll is the sync.
    }
}

// ---------------------------------------------------------------------------
extern "C" void kernel_launch(void* const* d_in, const int* in_sizes, int n_in,
                              void* d_out, int out_size, void* d_ws, size_t ws_size,
                              hipStream_t stream) {
    const float* x    = (const float*)d_in[0];
    const float* h0   = (const float*)d_in[1];
    const float* w_ih = (const float*)d_in[2];
    const float* w_hh = (const float*)d_in[3];
    const float* b_ih = (const float*)d_in[4];
    const float* b_hh = (const float*)d_in[5];
    float* out = (float*)d_out;

    char* p = (char*)d_ws;
    f16* wp16 = (f16*)p;   p += (size_t)I_SZ * G_SZ * 2;                 // 768 KB
    f16* wf16 = (f16*)p;   p += (size_t)NHS * GB * H_SZ * 2;             // 1.5 MB
    f16* hbuf = (f16*)p;   p += (size_t)(T_SEQ + 1) * NBS * PH * 2;      // 134 MB
    f16* gi   = (f16*)p;   // [T][NBS][G][MB] f16 = 402 MB (ws >= 808 MB proven)

    setup_kernel<<<2048, 256, 0, stream>>>(w_ih, w_hh, h0, wp16, wf16, hbuf);

    proj_kernel<<<T_SEQ * 4, 512, 0, stream>>>(x, wp16, b_ih, gi);

    gru_persist<<<NBS * NHS, GNTHR, 0, stream>>>(gi, wf16, h0, b_hh, hbuf, out);
}